// Round 4
// baseline (839.176 us; speedup 1.0000x reference)
//
// GCNTox21 fused pipeline — MI355X/gfx950.  R4: k_msg rewritten (LDS-staged
// pre-unpacked e_h, packed-f32 channel pairs, 4 nodes/block), merged probe +
// batched weight conversion, encoders read raw fp32/bf16 directly.
// Math (exact algebraic refactor):
//   P = h@w1[:,:in].T, Q = h@w1[:,in:2in].T    (node GEMMs, MFMA bf16)
//   u_e = relu(P[dst] + Q[src] + e_h[e]@w1[:,2in:].T + b1)
//   mean_u[n] = mean_{e:dst=n} u_e             (CSR over dst, built once)
//   h' = relu(BN(mean_u@w2.T + b2)), deg==0 rows -> BN(0)
//   out = sigmoid(mean_pool(h)@fc.T + fc_b)
#include <hip/hip_runtime.h>
#include <hip/hip_bf16.h>

typedef unsigned int  uint;
typedef unsigned short ushort;
typedef float  f32x2  __attribute__((ext_vector_type(2)));
typedef float  f32x4  __attribute__((ext_vector_type(4)));
typedef __bf16 bf16x8 __attribute__((ext_vector_type(8)));

#define DEV static __device__ __forceinline__

DEV float  b2f(ushort b){ return __uint_as_float(((uint)b) << 16); }
DEV float  lo2f(uint u){ return __uint_as_float(u << 16); }
DEV float  hi2f(uint u){ return __uint_as_float(u & 0xffff0000u); }
DEV ushort f2b(float f){           // RNE float->bf16
  uint u = __float_as_uint(f);
  u += 0x7fffu + ((u >> 16) & 1u);
  return (ushort)(u >> 16);
}
DEV uint pk2(float a, float b){ return (uint)f2b(a) | ((uint)f2b(b) << 16); }
DEV void unpack8(uint4 v, float* f){
  f[0]=lo2f(v.x); f[1]=hi2f(v.x); f[2]=lo2f(v.y); f[3]=hi2f(v.y);
  f[4]=lo2f(v.z); f[5]=hi2f(v.z); f[6]=lo2f(v.w); f[7]=hi2f(v.w);
}
DEV int ld_idx(const void* p, int flag, long long i){
  return flag ? ((const int*)p)[i] : (int)((const long long*)p)[i];
}
DEV int clampi(int v, int lo, int hi){ return v < lo ? lo : (v > hi ? hi : v); }

// ---------- merged probes: int64/int32 index layout + fp32/bf16 float layout ----------
__global__ void k_probes(const uint* __restrict__ ei, const uint* __restrict__ xw,
                         int* __restrict__ iflag, int* __restrict__ fflag){
  __shared__ int anyI, cntF;
  if (threadIdx.x == 0){ anyI = 0; cntF = 0; }
  __syncthreads();
  int li = 0, lc = 0;
  for (int i = threadIdx.x; i < 1024; i += 256){
    if (ei[2*i + 1] != 0u) li = 1;            // int64 => odd words all 0
    float f = fabsf(__uint_as_float(xw[i]));  // fp32 N(0,1) words decode sane
    if (f > 1e-6f && f < 1e6f) lc++;
  }
  if (li) atomicOr(&anyI, 1);
  atomicAdd(&cntF, lc);
  __syncthreads();
  if (threadIdx.x == 0){ *iflag = anyI; *fflag = (2*cntF > 1024) ? 1 : 0; }
}

// ---------- canonicalization ----------
__global__ __launch_bounds__(256) void k_canon(const void* __restrict__ src,
    const int* __restrict__ flag, int* __restrict__ out, int n){
  int i = blockIdx.x*256 + threadIdx.x;
  if (i >= n) return;
  out[i] = ld_idx(src, *flag, i);
}

struct CvtTab { const void* src[8]; ushort* dst[8]; int n[8]; int bstart[8]; int nseg; };
__global__ __launch_bounds__(256) void k_cvt_batch(CvtTab tab, const int* __restrict__ flag){
  int b = blockIdx.x;
  int s = tab.nseg - 1;
  for (int i = 1; i < tab.nseg; i++) if (b < tab.bstart[i]){ s = i - 1; break; }
  int rel = b - tab.bstart[s];
  const void* sp = tab.src[s];
  ushort* d = tab.dst[s];
  int f = *flag;
  int end = tab.n[s]; int cap = rel*8192 + 8192; if (cap < end) end = cap;
  for (int i = rel*8192 + threadIdx.x; i < end; i += 256)
    d[i] = f ? f2b(((const float*)sp)[i]) : ((const ushort*)sp)[i];
}

struct SmallTab { const void* src[24]; int doff[24]; int n[24]; };
__global__ __launch_bounds__(256) void k_cvt_small(SmallTab tab, const int* __restrict__ flag,
    ushort* __restrict__ base, int cnt){
  int b = blockIdx.x;
  if (b >= cnt) return;
  int f = *flag;
  const void* s = tab.src[b];
  ushort* d = base + tab.doff[b];
  for (int i = threadIdx.x; i < tab.n[b]; i += 256)
    d[i] = f ? f2b(((const float*)s)[i]) : ((const ushort*)s)[i];
}

// ---------- CSR build over dst ----------
__global__ __launch_bounds__(256) void k_count(const void* __restrict__ ei,
    const int* __restrict__ flag, int* __restrict__ cnt, int E, int N){
  int e = blockIdx.x*256 + threadIdx.x;
  if (e >= E) return;
  int d = clampi(ld_idx(ei, *flag, (long long)E + e), 0, N-1);
  atomicAdd(&cnt[d], 1);
}

__global__ __launch_bounds__(1024) void k_scan(const int* __restrict__ deg, int* __restrict__ rp, int n){
  __shared__ int part[1024];
  int t = threadIdx.x;
  int chunk = (n + 1023) >> 10;
  int base = t * chunk;
  int s = 0;
  for (int i = 0; i < chunk; i++){ int j = base + i; if (j < n) s += deg[j]; }
  part[t] = s;
  __syncthreads();
  for (int off = 1; off < 1024; off <<= 1){
    int v = (t >= off) ? part[t - off] : 0;
    __syncthreads();
    part[t] += v;
    __syncthreads();
  }
  int run = part[t] - s;
  for (int i = 0; i < chunk; i++){ int j = base + i; if (j < n){ rp[j] = run; run += deg[j]; } }
  if (t == 1023) rp[n] = part[1023];
}

__global__ __launch_bounds__(256) void k_fill(const void* __restrict__ ei,
    const int* __restrict__ flag, const int* __restrict__ rp, int* __restrict__ fill,
    int* __restrict__ csrc, int* __restrict__ ceid, int E, int N){
  int e = blockIdx.x*256 + threadIdx.x;
  if (e >= E) return;
  int f = *flag;
  int s = clampi(ld_idx(ei, f, e), 0, N-1);
  int d = clampi(ld_idx(ei, f, (long long)E + e), 0, N-1);
  int pos = clampi(rp[d] + atomicAdd(&fill[d], 1), 0, E-1);
  csrc[pos] = s;
  ceid[pos] = e;
}

// ---------- encoders (read raw fp32 or bf16 per fflag) ----------
__global__ __launch_bounds__(256) void k_edge_enc(const void* __restrict__ ea,
    const ushort* __restrict__ w, const ushort* __restrict__ b,
    const int* __restrict__ fflag, ushort* __restrict__ eh, int E){
  __shared__ float ws[128];
  __shared__ float bs[16];
  int t = threadIdx.x;
  if (t < 128) ws[t] = b2f(w[t]);
  if (t < 16)  bs[t] = b2f(b[t]);
  int f = *fflag;
  __syncthreads();
  int e = blockIdx.x*256 + t;
  if (e >= E) return;
  float a[8];
  if (f){
    const float4* ap = (const float4*)((const float*)ea + (size_t)e*8);
    float4 v0 = ap[0], v1 = ap[1];
    a[0]=v0.x; a[1]=v0.y; a[2]=v0.z; a[3]=v0.w;
    a[4]=v1.x; a[5]=v1.y; a[6]=v1.z; a[7]=v1.w;
  } else {
    uint4 av = *(const uint4*)((const ushort*)ea + (size_t)e*8);
    unpack8(av, a);
  }
  uint outp[8];
  #pragma unroll
  for (int o = 0; o < 16; o += 2){
    float s0 = bs[o], s1 = bs[o+1];
    #pragma unroll
    for (int j = 0; j < 8; j++){ s0 += a[j]*ws[o*8+j]; s1 += a[j]*ws[(o+1)*8+j]; }
    outp[o>>1] = pk2(fmaxf(s0, 0.f), fmaxf(s1, 0.f));
  }
  uint4* op = (uint4*)(eh + (size_t)e*16);
  op[0] = make_uint4(outp[0], outp[1], outp[2], outp[3]);
  op[1] = make_uint4(outp[4], outp[5], outp[6], outp[7]);
}

__global__ __launch_bounds__(256) void k_node_enc(const void* __restrict__ x,
    const ushort* __restrict__ w, const ushort* __restrict__ b,
    const int* __restrict__ fflag, ushort* __restrict__ h, int N){
  __shared__ float xs[32];
  int n = blockIdx.x, t = threadIdx.x;
  int f = *fflag;
  if (t < 32) xs[t] = f ? ((const float*)x)[(size_t)n*32 + t]
                        : b2f(((const ushort*)x)[(size_t)n*32 + t]);
  __syncthreads();
  const uint4* wp = (const uint4*)(w + (size_t)t*32);
  float s = b2f(b[t]);
  #pragma unroll
  for (int q4 = 0; q4 < 4; q4++){
    uint4 u = wp[q4];
    int k = q4*8;
    s += xs[k+0]*lo2f(u.x) + xs[k+1]*hi2f(u.x)
       + xs[k+2]*lo2f(u.y) + xs[k+3]*hi2f(u.y)
       + xs[k+4]*lo2f(u.z) + xs[k+5]*hi2f(u.z)
       + xs[k+6]*lo2f(u.w) + xs[k+7]*hi2f(u.w);
  }
  h[(size_t)n*256 + t] = f2b(fmaxf(s, 0.f));
}

// ---------- MFMA GEMM: C[M,Nc] = A[M,K(lda)] @ W[Nc,K(ldb)]^T ----------
__global__ __launch_bounds__(256) void k_gemm_p(const ushort* __restrict__ A, int lda,
    const ushort* __restrict__ W, int ldb, int M, int Nc, int K, ushort* __restrict__ C){
  const int l  = threadIdx.x & 63;
  const int wv = threadIdx.x >> 6;
  const int m0 = blockIdx.x*64 + wv*16;
  const int n0 = blockIdx.y*64;
  const int lr = l & 15;
  const int q  = l >> 4;
  int ar = m0 + lr; if (ar >= M) ar = M - 1;
  const ushort* Ap = A + (size_t)ar*lda + q*8;
  const ushort* Wp = W + (size_t)(n0 + lr)*ldb + q*8;
  f32x4 acc[4] = {{0.f,0.f,0.f,0.f},{0.f,0.f,0.f,0.f},{0.f,0.f,0.f,0.f},{0.f,0.f,0.f,0.f}};
  for (int k = 0; k < K; k += 32){
    bf16x8 a = *(const bf16x8*)(Ap + k);
    #pragma unroll
    for (int nf = 0; nf < 4; nf++){
      bf16x8 b = *(const bf16x8*)(Wp + (size_t)nf*16*ldb + k);
      acc[nf] = __builtin_amdgcn_mfma_f32_16x16x32_bf16(a, b, acc[nf], 0, 0, 0);
    }
  }
  #pragma unroll
  for (int nf = 0; nf < 4; nf++){
    int col = n0 + nf*16 + lr;
    #pragma unroll
    for (int r = 0; r < 4; r++){
      int row = m0 + q*4 + r;
      if (row < M) C[(size_t)row*Nc + col] = f2b(acc[nf][r]);
    }
  }
}

__global__ __launch_bounds__(256) void k_gemm_bn(const ushort* __restrict__ A, int lda,
    const ushort* __restrict__ W, int ldb, int M, int Nc, int K,
    const ushort* __restrict__ bias, const ushort* __restrict__ g, const ushort* __restrict__ bb,
    const ushort* __restrict__ rm, const ushort* __restrict__ rv,
    const int* __restrict__ rp, ushort* __restrict__ H){
  const int l  = threadIdx.x & 63;
  const int wv = threadIdx.x >> 6;
  const int m0 = blockIdx.x*64 + wv*16;
  const int n0 = blockIdx.y*64;
  const int lr = l & 15;
  const int q  = l >> 4;
  int ar = m0 + lr; if (ar >= M) ar = M - 1;
  const ushort* Ap = A + (size_t)ar*lda + q*8;
  const ushort* Wp = W + (size_t)(n0 + lr)*ldb + q*8;
  f32x4 acc[4] = {{0.f,0.f,0.f,0.f},{0.f,0.f,0.f,0.f},{0.f,0.f,0.f,0.f},{0.f,0.f,0.f,0.f}};
  for (int k = 0; k < K; k += 32){
    bf16x8 a = *(const bf16x8*)(Ap + k);
    #pragma unroll
    for (int nf = 0; nf < 4; nf++){
      bf16x8 b = *(const bf16x8*)(Wp + (size_t)nf*16*ldb + k);
      acc[nf] = __builtin_amdgcn_mfma_f32_16x16x32_bf16(a, b, acc[nf], 0, 0, 0);
    }
  }
  #pragma unroll
  for (int nf = 0; nf < 4; nf++){
    int col = n0 + nf*16 + lr;
    float bi = b2f(bias[col]);
    float sc = b2f(g[col]) * rsqrtf(b2f(rv[col]) + 1e-5f);
    float sh = b2f(bb[col]) - b2f(rm[col]) * sc;
    #pragma unroll
    for (int r = 0; r < 4; r++){
      int row = m0 + q*4 + r;
      if (row < M){
        float v = acc[nf][r] + bi;
        if (rp[row+1] - rp[row] == 0) v = 0.f;   // empty segment: mean is 0
        H[(size_t)row*Nc + col] = f2b(fmaxf(v*sc + sh, 0.f));
      }
    }
  }
}

// ---------- per-node edge aggregation v2 ----------
// 4 nodes/block; 64-edge chunks of e_h staged to LDS pre-unpacked (f32);
// thread t owns channels {2t, 2t+1} as a packed f32x2.  MU may alias P:
// block only touches its own 4 rows; each row read before written.
template<int NCOMP>   // compute threads = C/2
__global__ __launch_bounds__(256) void k_msg2(const ushort* P, const ushort* __restrict__ Q,
    const ushort* __restrict__ eh, const ushort* __restrict__ w1, const ushort* __restrict__ b1,
    const int* __restrict__ rp, const int* __restrict__ csrc, const int* __restrict__ ceid,
    ushort* MU, int N){
  const int C = NCOMP*2;
  int t = threadIdx.x;
  bool act = (t < NCOMP);
  int c0 = t*2;
  f32x2 wc2[16]; f32x2 b1v;
  if (act){
    float a0[16], a1[16];
    const uint4* wp0 = (const uint4*)(w1 + (size_t)c0*528 + 512);
    const uint4* wp1 = (const uint4*)(w1 + (size_t)(c0+1)*528 + 512);
    unpack8(wp0[0], a0); unpack8(wp0[1], a0+8);
    unpack8(wp1[0], a1); unpack8(wp1[1], a1+8);
    #pragma unroll
    for (int j = 0; j < 16; j++){ wc2[j].x = a0[j]; wc2[j].y = a1[j]; }
    uint bw = *(const uint*)(b1 + c0);
    b1v.x = lo2f(bw); b1v.y = hi2f(bw);
  }
  __shared__ float sef[64][16];
  __shared__ int   ssrc[64];
  int nbeg = blockIdx.x*4;
  int nend = nbeg + 4; if (nend > N) nend = N;
  for (int n = nbeg; n < nend; n++){
    const int i0 = rp[n], i1 = rp[n+1];
    f32x2 acc = {0.f, 0.f};
    f32x2 pre = {0.f, 0.f};
    if (act){
      uint pw = *(const uint*)(P + (size_t)n*C + c0);
      pre.x = lo2f(pw) + b1v.x; pre.y = hi2f(pw) + b1v.y;
    }
    for (int base = i0; base < i1; base += 64){
      int cnt = i1 - base; if (cnt > 64) cnt = 64;
      __syncthreads();
      if (t < 2*cnt){
        int ie = t >> 1, hf = t & 1;
        int eid = ceid[base + ie];
        uint4 v = *(const uint4*)(eh + (size_t)eid*16 + hf*8);
        unpack8(v, &sef[ie][hf*8]);
      }
      if (t >= 128 && t < 128 + cnt) ssrc[t - 128] = csrc[base + t - 128];
      __syncthreads();
      if (act){
        for (int i = 0; i < cnt; i++){
          int src = ssrc[i];
          uint qw = *(const uint*)(Q + (size_t)src*C + c0);
          f32x2 d; d.x = pre.x + lo2f(qw); d.y = pre.y + hi2f(qw);
          const float* ef = sef[i];
          #pragma unroll
          for (int j = 0; j < 16; j++){
            f32x2 e2 = {ef[j], ef[j]};
            d += wc2[j] * e2;
          }
          d.x = fmaxf(d.x, 0.f); d.y = fmaxf(d.y, 0.f);
          acc += d;
        }
      }
    }
    if (act){
      int cnt = i1 - i0;
      float inv = (cnt > 0) ? 1.f/(float)cnt : 0.f;
      *(uint*)(MU + (size_t)n*C + c0) = pk2(acc.x*inv, acc.y*inv);
    }
  }
}

// ---------- pooling + FC + sigmoid ----------
__global__ __launch_bounds__(128) void k_pool(const ushort* __restrict__ h, const int* __restrict__ batch,
    const ushort* __restrict__ fw, const ushort* __restrict__ fb,
    const int* __restrict__ fflag, void* __restrict__ out, int N){
  int g = blockIdx.x, t = threadIdx.x;
  int lo = 0, hi = N;
  while (lo < hi){ int mid = (lo+hi) >> 1; if (batch[mid] <  g) lo = mid+1; else hi = mid; }
  int s0 = lo;
  hi = N;
  while (lo < hi){ int mid = (lo+hi) >> 1; if (batch[mid] <= g) lo = mid+1; else hi = mid; }
  int s1 = lo;
  float s = 0.f;
  for (int i = s0; i < s1; i++) s += b2f(h[(size_t)i*128 + t]);
  int cnt = s1 - s0;
  __shared__ float ps[128];
  ps[t] = s / (float)(cnt > 0 ? cnt : 1);
  __syncthreads();
  if (t < 12){
    float z = b2f(fb[t]);
    for (int j = 0; j < 128; j++) z += ps[j]*b2f(fw[t*128 + j]);
    float r = 1.f/(1.f + expf(-z));
    if (*fflag) ((float*)out)[g*12 + t] = r;
    else        ((ushort*)out)[g*12 + t] = f2b(r);
  }
}

__global__ __launch_bounds__(256) void k_sentinel(ushort* __restrict__ out, int n){
  int i = blockIdx.x*256 + threadIdx.x;
  if (i < n) out[i] = 0x3F00;
}

extern "C" void kernel_launch(void* const* d_in, const int* in_sizes, int n_in,
                              void* d_out, int out_size, void* d_ws, size_t ws_size,
                              hipStream_t stream){
  const void* x_raw   = d_in[0];
  const void* ei_raw  = d_in[1];
  const void* ea_raw  = d_in[2];
  const void* ba_raw  = d_in[3];
  (void)n_in;

  const int N = in_sizes[3];        // 20000
  const int E = in_sizes[1] / 2;    // 200000
  const int G = out_size / 12;      // 512

  // ---- workspace plan ----
  char* base = (char*)d_ws;
  size_t off = 0;
  auto alloc = [&](size_t bytes)->char*{
    char* p = base + off;
    off = (off + bytes + 255) & ~(size_t)255;
    return p;
  };
  int* iflag    = (int*)alloc(256);
  int* fflag    = (int*)alloc(256);
  int* deg      = (int*)alloc((size_t)N*4);
  int* fill     = (int*)alloc((size_t)N*4);
  int* rp       = (int*)alloc((size_t)(N+1)*4);
  int* batch2   = (int*)alloc((size_t)N*4);
  int* csrc     = (int*)alloc((size_t)E*4);
  int* ceid     = (int*)alloc((size_t)E*4);
  ushort* new_c = (ushort*)alloc(8192*2);
  ushort* w1c[3], *w2c[3];
  const int w1n[3] = {512*528, 512*528, 256*528};
  const int w2n[3] = {256*512, 256*512, 128*256};
  for (int i = 0; i < 3; i++) w1c[i] = (ushort*)alloc((size_t)w1n[i]*2);
  for (int i = 0; i < 3; i++) w2c[i] = (ushort*)alloc((size_t)w2n[i]*2);
  ushort* smallp = (ushort*)alloc(8192*2);
  ushort* e_h   = (ushort*)alloc((size_t)E*16*2);
  ushort* h     = (ushort*)alloc((size_t)N*256*2);
  ushort* Q     = (ushort*)alloc((size_t)N*512*2);
  ushort* PM    = (ushort*)alloc((size_t)N*512*2);

  if (off > ws_size){
    k_sentinel<<<(out_size + 255)/256, 256, 0, stream>>>((ushort*)d_out, out_size);
    return;
  }

  // ---- probes + CSR ----
  k_probes<<<1, 256, 0, stream>>>((const uint*)ei_raw, (const uint*)x_raw, iflag, fflag);
  k_canon<<<(N + 255)/256, 256, 0, stream>>>(ba_raw, iflag, batch2, N);
  hipMemsetAsync(deg,  0, (size_t)N*4, stream);
  hipMemsetAsync(fill, 0, (size_t)N*4, stream);
  k_count<<<(E + 255)/256, 256, 0, stream>>>(ei_raw, iflag, deg, E, N);
  k_scan<<<1, 1024, 0, stream>>>(deg, rp, N);
  k_fill<<<(E + 255)/256, 256, 0, stream>>>(ei_raw, iflag, rp, fill, csrc, ceid, E, N);

  // ---- batched weight conversion (w1 x3, w2 x3, ne_w) ----
  CvtTab ct; ct.nseg = 7;
  const void* csrcs[7] = {d_in[8], d_in[16], d_in[24], d_in[10], d_in[18], d_in[26], d_in[6]};
  ushort* cdsts[7]     = {w1c[0],  w1c[1],   w1c[2],   w2c[0],   w2c[1],   w2c[2],   new_c};
  const int cns[7]     = {w1n[0],  w1n[1],   w1n[2],   w2n[0],   w2n[1],   w2n[2],   8192};
  int bacc = 0;
  for (int i = 0; i < 7; i++){
    ct.src[i] = csrcs[i]; ct.dst[i] = cdsts[i]; ct.n[i] = cns[i];
    ct.bstart[i] = bacc; bacc += (cns[i] + 8191)/8192;
  }
  k_cvt_batch<<<bacc, 256, 0, stream>>>(ct, fflag);

  // ---- small vectors packed ----
  SmallTab tab;
  int scount = 0, spos = 0;
  auto addsmall = [&](int di, int n)->int{
    int p = spos;
    tab.src[scount] = d_in[di]; tab.doff[scount] = spos; tab.n[scount] = n;
    spos += n; scount++;
    return p;
  };
  int pos_eew  = addsmall(4, 128);
  int pos_eeb  = addsmall(5, 16);
  int pos_neb  = addsmall(7, 256);
  int pos_b1[3], pos_b2[3], pos_g[3], pos_bb[3], pos_m[3], pos_v[3];
  const int b1n[3] = {512,512,256}, b2n[3] = {256,256,128}, bnn[3] = {256,256,128};
  for (int i = 0; i < 3; i++){
    int di = 8 + 8*i;
    pos_b1[i] = addsmall(di+1, b1n[i]);
    pos_b2[i] = addsmall(di+3, b2n[i]);
    pos_g[i]  = addsmall(di+4, bnn[i]);
    pos_bb[i] = addsmall(di+5, bnn[i]);
    pos_m[i]  = addsmall(di+6, bnn[i]);
    pos_v[i]  = addsmall(di+7, bnn[i]);
  }
  int pos_fcw = addsmall(32, 12*128);
  int pos_fcb = addsmall(33, 12);
  k_cvt_small<<<scount, 256, 0, stream>>>(tab, fflag, smallp, scount);

  // ---- encoders ----
  k_edge_enc<<<(E + 255)/256, 256, 0, stream>>>(ea_raw, smallp + pos_eew, smallp + pos_eeb, fflag, e_h, E);
  k_node_enc<<<N, 256, 0, stream>>>(x_raw, new_c, smallp + pos_neb, fflag, h, N);

  // ---- 3 conv layers ----
  const int Cch[3] = {512, 512, 256};
  const int Od[3]  = {256, 256, 128};
  for (int i = 0; i < 3; i++){
    dim3 g1((N + 63)/64, Cch[i]/64);
    k_gemm_p<<<g1, 256, 0, stream>>>(h, 256, w1c[i],       528, N, Cch[i], 256, PM);
    k_gemm_p<<<g1, 256, 0, stream>>>(h, 256, w1c[i] + 256, 528, N, Cch[i], 256, Q);
    dim3 gm((N + 3)/4);
    if (i < 2) k_msg2<256><<<gm, 256, 0, stream>>>(PM, Q, e_h, w1c[i], smallp + pos_b1[i], rp, csrc, ceid, PM, N);
    else       k_msg2<128><<<gm, 256, 0, stream>>>(PM, Q, e_h, w1c[i], smallp + pos_b1[i], rp, csrc, ceid, PM, N);
    dim3 g2((N + 63)/64, Od[i]/64);
    k_gemm_bn<<<g2, 256, 0, stream>>>(PM, Cch[i], w2c[i], Cch[i], N, Od[i], Cch[i],
                                      smallp + pos_b2[i], smallp + pos_g[i], smallp + pos_bb[i],
                                      smallp + pos_m[i],  smallp + pos_v[i], rp, h);
  }

  // ---- mean pool + FC + sigmoid ----
  k_pool<<<G, 128, 0, stream>>>(h, batch2, smallp + pos_fcw, smallp + pos_fcb, fflag, d_out, N);
}

// Round 5
// 676.410 us; speedup vs baseline: 1.2406x; 1.2406x over previous
//
// GCNTox21 fused pipeline — MI355X/gfx950.  R5: k_msg back to R3's barrier-free
// per-node shape but with f32-preunpacked e_h + packed f32x2 math (v_pk_fma);
// P/Q GEMMs merged into one launch; GEMM waves widened to 32 rows (8 MFMA / 6
// loads per k-step).  R4's LDS staging regressed (occupancy 75->46, 16-way LDS
// write conflicts) — reverted.
// Math (exact algebraic refactor):
//   P = h@w1[:,:in].T, Q = h@w1[:,in:2in].T    (node GEMMs, MFMA bf16)
//   u_e = relu(P[dst] + Q[src] + e_h[e]@w1[:,2in:].T + b1)
//   mean_u[n] = mean_{e:dst=n} u_e             (CSR over dst, built once)
//   h' = relu(BN(mean_u@w2.T + b2)), deg==0 rows -> BN(0)
//   out = sigmoid(mean_pool(h)@fc.T + fc_b)
#include <hip/hip_runtime.h>
#include <hip/hip_bf16.h>

typedef unsigned int  uint;
typedef unsigned short ushort;
typedef float  f32x2  __attribute__((ext_vector_type(2)));
typedef float  f32x4  __attribute__((ext_vector_type(4)));
typedef __bf16 bf16x8 __attribute__((ext_vector_type(8)));

#define DEV static __device__ __forceinline__

DEV float  b2f(ushort b){ return __uint_as_float(((uint)b) << 16); }
DEV float  lo2f(uint u){ return __uint_as_float(u << 16); }
DEV float  hi2f(uint u){ return __uint_as_float(u & 0xffff0000u); }
DEV ushort f2b(float f){           // RNE float->bf16
  uint u = __float_as_uint(f);
  u += 0x7fffu + ((u >> 16) & 1u);
  return (ushort)(u >> 16);
}
DEV uint pk2(float a, float b){ return (uint)f2b(a) | ((uint)f2b(b) << 16); }
DEV void unpack8(uint4 v, float* f){
  f[0]=lo2f(v.x); f[1]=hi2f(v.x); f[2]=lo2f(v.y); f[3]=hi2f(v.y);
  f[4]=lo2f(v.z); f[5]=hi2f(v.z); f[6]=lo2f(v.w); f[7]=hi2f(v.w);
}
DEV int ld_idx(const void* p, int flag, long long i){
  return flag ? ((const int*)p)[i] : (int)((const long long*)p)[i];
}
DEV int clampi(int v, int lo, int hi){ return v < lo ? lo : (v > hi ? hi : v); }

// ---------- merged probes: int64/int32 index layout + fp32/bf16 float layout ----------
__global__ void k_probes(const uint* __restrict__ ei, const uint* __restrict__ xw,
                         int* __restrict__ iflag, int* __restrict__ fflag){
  __shared__ int anyI, cntF;
  if (threadIdx.x == 0){ anyI = 0; cntF = 0; }
  __syncthreads();
  int li = 0, lc = 0;
  for (int i = threadIdx.x; i < 1024; i += 256){
    if (ei[2*i + 1] != 0u) li = 1;            // int64 => odd words all 0
    float f = fabsf(__uint_as_float(xw[i]));  // fp32 N(0,1) words decode sane
    if (f > 1e-6f && f < 1e6f) lc++;
  }
  if (li) atomicOr(&anyI, 1);
  atomicAdd(&cntF, lc);
  __syncthreads();
  if (threadIdx.x == 0){ *iflag = anyI; *fflag = (2*cntF > 1024) ? 1 : 0; }
}

// ---------- canonicalization ----------
__global__ __launch_bounds__(256) void k_canon(const void* __restrict__ src,
    const int* __restrict__ flag, int* __restrict__ out, int n){
  int i = blockIdx.x*256 + threadIdx.x;
  if (i >= n) return;
  out[i] = ld_idx(src, *flag, i);
}

struct CvtTab { const void* src[8]; ushort* dst[8]; int n[8]; int bstart[8]; int nseg; };
__global__ __launch_bounds__(256) void k_cvt_batch(CvtTab tab, const int* __restrict__ flag){
  int b = blockIdx.x;
  int s = tab.nseg - 1;
  for (int i = 1; i < tab.nseg; i++) if (b < tab.bstart[i]){ s = i - 1; break; }
  int rel = b - tab.bstart[s];
  const void* sp = tab.src[s];
  ushort* d = tab.dst[s];
  int f = *flag;
  int end = tab.n[s]; int cap = rel*8192 + 8192; if (cap < end) end = cap;
  for (int i = rel*8192 + threadIdx.x; i < end; i += 256)
    d[i] = f ? f2b(((const float*)sp)[i]) : ((const ushort*)sp)[i];
}

struct SmallTab { const void* src[24]; int doff[24]; int n[24]; };
__global__ __launch_bounds__(256) void k_cvt_small(SmallTab tab, const int* __restrict__ flag,
    ushort* __restrict__ base, int cnt){
  int b = blockIdx.x;
  if (b >= cnt) return;
  int f = *flag;
  const void* s = tab.src[b];
  ushort* d = base + tab.doff[b];
  for (int i = threadIdx.x; i < tab.n[b]; i += 256)
    d[i] = f ? f2b(((const float*)s)[i]) : ((const ushort*)s)[i];
}

// ---------- CSR build over dst ----------
__global__ __launch_bounds__(256) void k_count(const void* __restrict__ ei,
    const int* __restrict__ flag, int* __restrict__ cnt, int E, int N){
  int e = blockIdx.x*256 + threadIdx.x;
  if (e >= E) return;
  int d = clampi(ld_idx(ei, *flag, (long long)E + e), 0, N-1);
  atomicAdd(&cnt[d], 1);
}

__global__ __launch_bounds__(1024) void k_scan(const int* __restrict__ deg, int* __restrict__ rp, int n){
  __shared__ int part[1024];
  int t = threadIdx.x;
  int chunk = (n + 1023) >> 10;
  int base = t * chunk;
  int s = 0;
  for (int i = 0; i < chunk; i++){ int j = base + i; if (j < n) s += deg[j]; }
  part[t] = s;
  __syncthreads();
  for (int off = 1; off < 1024; off <<= 1){
    int v = (t >= off) ? part[t - off] : 0;
    __syncthreads();
    part[t] += v;
    __syncthreads();
  }
  int run = part[t] - s;
  for (int i = 0; i < chunk; i++){ int j = base + i; if (j < n){ rp[j] = run; run += deg[j]; } }
  if (t == 1023) rp[n] = part[1023];
}

__global__ __launch_bounds__(256) void k_fill(const void* __restrict__ ei,
    const int* __restrict__ flag, const int* __restrict__ rp, int* __restrict__ fill,
    int* __restrict__ csrc, int* __restrict__ ceid, int E, int N){
  int e = blockIdx.x*256 + threadIdx.x;
  if (e >= E) return;
  int f = *flag;
  int s = clampi(ld_idx(ei, f, e), 0, N-1);
  int d = clampi(ld_idx(ei, f, (long long)E + e), 0, N-1);
  int pos = clampi(rp[d] + atomicAdd(&fill[d], 1), 0, E-1);
  csrc[pos] = s;
  ceid[pos] = e;
}

// ---------- encoders ----------
// e_h32[E,16] = relu(edge_attr @ ee_w.T + ee_b), stored PRE-UNPACKED f32
__global__ __launch_bounds__(256) void k_edge_enc(const void* __restrict__ ea,
    const ushort* __restrict__ w, const ushort* __restrict__ b,
    const int* __restrict__ fflag, float* __restrict__ eh, int E){
  __shared__ float ws[128];
  __shared__ float bs[16];
  int t = threadIdx.x;
  if (t < 128) ws[t] = b2f(w[t]);
  if (t < 16)  bs[t] = b2f(b[t]);
  int f = *fflag;
  __syncthreads();
  int e = blockIdx.x*256 + t;
  if (e >= E) return;
  float a[8];
  if (f){
    const float4* ap = (const float4*)((const float*)ea + (size_t)e*8);
    float4 v0 = ap[0], v1 = ap[1];
    a[0]=v0.x; a[1]=v0.y; a[2]=v0.z; a[3]=v0.w;
    a[4]=v1.x; a[5]=v1.y; a[6]=v1.z; a[7]=v1.w;
  } else {
    uint4 av = *(const uint4*)((const ushort*)ea + (size_t)e*8);
    unpack8(av, a);
  }
  float o[16];
  #pragma unroll
  for (int c = 0; c < 16; c++){
    float s = bs[c];
    #pragma unroll
    for (int j = 0; j < 8; j++) s += a[j]*ws[c*8+j];
    o[c] = fmaxf(s, 0.f);
  }
  f32x4* op = (f32x4*)(eh + (size_t)e*16);
  #pragma unroll
  for (int q4 = 0; q4 < 4; q4++){
    f32x4 v = {o[q4*4+0], o[q4*4+1], o[q4*4+2], o[q4*4+3]};
    op[q4] = v;
  }
}

__global__ __launch_bounds__(256) void k_node_enc(const void* __restrict__ x,
    const ushort* __restrict__ w, const ushort* __restrict__ b,
    const int* __restrict__ fflag, ushort* __restrict__ h, int N){
  __shared__ float xs[32];
  int n = blockIdx.x, t = threadIdx.x;
  int f = *fflag;
  if (t < 32) xs[t] = f ? ((const float*)x)[(size_t)n*32 + t]
                        : b2f(((const ushort*)x)[(size_t)n*32 + t]);
  __syncthreads();
  const uint4* wp = (const uint4*)(w + (size_t)t*32);
  float s = b2f(b[t]);
  #pragma unroll
  for (int q4 = 0; q4 < 4; q4++){
    uint4 u = wp[q4];
    int k = q4*8;
    s += xs[k+0]*lo2f(u.x) + xs[k+1]*hi2f(u.x)
       + xs[k+2]*lo2f(u.y) + xs[k+3]*hi2f(u.y)
       + xs[k+4]*lo2f(u.z) + xs[k+5]*hi2f(u.z)
       + xs[k+6]*lo2f(u.w) + xs[k+7]*hi2f(u.w);
  }
  h[(size_t)n*256 + t] = f2b(fmaxf(s, 0.f));
}

// ---------- merged P/Q GEMM, 32-row waves ----------
// A = h [M,256]; blockIdx.y < Nc/64 -> P (w1 cols 0..255), else Q (cols 256..511).
// Wave: 32 rows x 64 cols; per k-step 2 A-loads + 4 B-loads, 8 MFMA.
__global__ __launch_bounds__(256) void k_gemm_pq(const ushort* __restrict__ A,
    const ushort* __restrict__ w1, int M, int Nc,
    ushort* __restrict__ P, ushort* __restrict__ Q){
  const int l  = threadIdx.x & 63;
  const int wv = threadIdx.x >> 6;
  const int m0 = blockIdx.x*128 + wv*32;
  const int yc = Nc >> 6;
  const int isQ = (int)blockIdx.y >= yc;
  const int n0 = (isQ ? blockIdx.y - yc : blockIdx.y)*64;
  const ushort* W = w1 + (isQ ? 256 : 0);
  ushort* C = isQ ? Q : P;
  const int lr = l & 15;
  const int q  = l >> 4;
  int ar0 = m0 + lr;      if (ar0 >= M) ar0 = M - 1;
  int ar1 = m0 + 16 + lr; if (ar1 >= M) ar1 = M - 1;
  const ushort* Ap0 = A + (size_t)ar0*256 + q*8;
  const ushort* Ap1 = A + (size_t)ar1*256 + q*8;
  const ushort* Wp = W + (size_t)(n0 + lr)*528 + q*8;
  f32x4 acc[2][4];
  #pragma unroll
  for (int f = 0; f < 2; f++)
    #pragma unroll
    for (int nf = 0; nf < 4; nf++) acc[f][nf] = {0.f,0.f,0.f,0.f};
  #pragma unroll
  for (int k = 0; k < 256; k += 32){
    bf16x8 a0 = *(const bf16x8*)(Ap0 + k);
    bf16x8 a1 = *(const bf16x8*)(Ap1 + k);
    #pragma unroll
    for (int nf = 0; nf < 4; nf++){
      bf16x8 b = *(const bf16x8*)(Wp + (size_t)nf*16*528 + k);
      acc[0][nf] = __builtin_amdgcn_mfma_f32_16x16x32_bf16(a0, b, acc[0][nf], 0, 0, 0);
      acc[1][nf] = __builtin_amdgcn_mfma_f32_16x16x32_bf16(a1, b, acc[1][nf], 0, 0, 0);
    }
  }
  #pragma unroll
  for (int f = 0; f < 2; f++){
    #pragma unroll
    for (int nf = 0; nf < 4; nf++){
      int col = n0 + nf*16 + lr;
      #pragma unroll
      for (int r = 0; r < 4; r++){
        int row = m0 + 16*f + q*4 + r;
        if (row < M) C[(size_t)row*Nc + col] = f2b(acc[f][nf][r]);
      }
    }
  }
}

// GEMM + bias + deg-mask + eval-BN + relu, 32-row waves
__global__ __launch_bounds__(256) void k_gemm_bn(const ushort* __restrict__ A, int lda,
    const ushort* __restrict__ W, int ldb, int M, int Nc, int K,
    const ushort* __restrict__ bias, const ushort* __restrict__ g, const ushort* __restrict__ bb,
    const ushort* __restrict__ rm, const ushort* __restrict__ rv,
    const int* __restrict__ rp, ushort* __restrict__ H){
  const int l  = threadIdx.x & 63;
  const int wv = threadIdx.x >> 6;
  const int m0 = blockIdx.x*128 + wv*32;
  const int n0 = blockIdx.y*64;
  const int lr = l & 15;
  const int q  = l >> 4;
  int ar0 = m0 + lr;      if (ar0 >= M) ar0 = M - 1;
  int ar1 = m0 + 16 + lr; if (ar1 >= M) ar1 = M - 1;
  const ushort* Ap0 = A + (size_t)ar0*lda + q*8;
  const ushort* Ap1 = A + (size_t)ar1*lda + q*8;
  const ushort* Wp = W + (size_t)(n0 + lr)*ldb + q*8;
  f32x4 acc[2][4];
  #pragma unroll
  for (int f = 0; f < 2; f++)
    #pragma unroll
    for (int nf = 0; nf < 4; nf++) acc[f][nf] = {0.f,0.f,0.f,0.f};
  for (int k = 0; k < K; k += 32){
    bf16x8 a0 = *(const bf16x8*)(Ap0 + k);
    bf16x8 a1 = *(const bf16x8*)(Ap1 + k);
    #pragma unroll
    for (int nf = 0; nf < 4; nf++){
      bf16x8 b = *(const bf16x8*)(Wp + (size_t)nf*16*ldb + k);
      acc[0][nf] = __builtin_amdgcn_mfma_f32_16x16x32_bf16(a0, b, acc[0][nf], 0, 0, 0);
      acc[1][nf] = __builtin_amdgcn_mfma_f32_16x16x32_bf16(a1, b, acc[1][nf], 0, 0, 0);
    }
  }
  #pragma unroll
  for (int nf = 0; nf < 4; nf++){
    int col = n0 + nf*16 + lr;
    float bi = b2f(bias[col]);
    float sc = b2f(g[col]) * rsqrtf(b2f(rv[col]) + 1e-5f);
    float sh = b2f(bb[col]) - b2f(rm[col]) * sc;
    #pragma unroll
    for (int f = 0; f < 2; f++){
      #pragma unroll
      for (int r = 0; r < 4; r++){
        int row = m0 + 16*f + q*4 + r;
        if (row < M){
          float v = acc[f][nf][r] + bi;
          if (rp[row+1] - rp[row] == 0) v = 0.f;   // empty segment: mean is 0
          H[(size_t)row*Nc + col] = f2b(fmaxf(v*sc + sh, 0.f));
        }
      }
    }
  }
}

// ---------- per-node edge aggregation v3 (R3 shape, f32 e_h, packed pairs) ----
// One node per block, C/2 threads, thread t owns channels {2t,2t+1} as f32x2.
// No barriers, no LDS.  MU may alias P (block touches only row n; read-before-write).
template<int C>
__global__ __launch_bounds__(256) void k_msg3(const ushort* P, const ushort* __restrict__ Q,
    const float* __restrict__ eh, const ushort* __restrict__ w1, const ushort* __restrict__ b1,
    const int* __restrict__ rp, const int* __restrict__ csrc, const int* __restrict__ ceid,
    ushort* MU, int N){
  int n = blockIdx.x;
  int t = threadIdx.x;
  int c0 = t*2;
  f32x2 wc[16];
  {
    float a0[16], a1[16];
    const uint4* wp0 = (const uint4*)(w1 + (size_t)c0*528 + 512);
    const uint4* wp1 = (const uint4*)(w1 + (size_t)(c0+1)*528 + 512);
    unpack8(wp0[0], a0); unpack8(wp0[1], a0+8);
    unpack8(wp1[0], a1); unpack8(wp1[1], a1+8);
    #pragma unroll
    for (int j = 0; j < 16; j++){ wc[j].x = a0[j]; wc[j].y = a1[j]; }
  }
  uint bw = *(const uint*)(b1 + c0);
  uint pw = *(const uint*)(P + (size_t)n*C + c0);
  f32x2 pre = { lo2f(pw) + lo2f(bw), hi2f(pw) + hi2f(bw) };
  f32x2 acc = {0.f, 0.f};
  const int i0 = rp[n], i1 = rp[n+1];
  for (int i = i0; i < i1; ++i){
    int src = csrc[i], eid = ceid[i];
    uint qw = *(const uint*)(Q + (size_t)src*C + c0);
    const f32x4* ep = (const f32x4*)(eh + (size_t)eid*16);
    f32x4 e0 = ep[0], e1 = ep[1], e2 = ep[2], e3 = ep[3];
    float ef[16] = {e0.x,e0.y,e0.z,e0.w, e1.x,e1.y,e1.z,e1.w,
                    e2.x,e2.y,e2.z,e2.w, e3.x,e3.y,e3.z,e3.w};
    f32x2 d = { pre.x + lo2f(qw), pre.y + hi2f(qw) };
    #pragma unroll
    for (int j = 0; j < 16; j++){
      f32x2 e2v = {ef[j], ef[j]};
      d += wc[j] * e2v;
    }
    d.x = fmaxf(d.x, 0.f); d.y = fmaxf(d.y, 0.f);
    acc += d;
  }
  int cnt = i1 - i0;
  float inv = (cnt > 0) ? 1.f/(float)cnt : 0.f;
  *(uint*)(MU + (size_t)n*C + c0) = pk2(acc.x*inv, acc.y*inv);
}

// ---------- pooling + FC + sigmoid ----------
__global__ __launch_bounds__(128) void k_pool(const ushort* __restrict__ h, const int* __restrict__ batch,
    const ushort* __restrict__ fw, const ushort* __restrict__ fb,
    const int* __restrict__ fflag, void* __restrict__ out, int N){
  int g = blockIdx.x, t = threadIdx.x;
  int lo = 0, hi = N;
  while (lo < hi){ int mid = (lo+hi) >> 1; if (batch[mid] <  g) lo = mid+1; else hi = mid; }
  int s0 = lo;
  hi = N;
  while (lo < hi){ int mid = (lo+hi) >> 1; if (batch[mid] <= g) lo = mid+1; else hi = mid; }
  int s1 = lo;
  float s = 0.f;
  for (int i = s0; i < s1; i++) s += b2f(h[(size_t)i*128 + t]);
  int cnt = s1 - s0;
  __shared__ float ps[128];
  ps[t] = s / (float)(cnt > 0 ? cnt : 1);
  __syncthreads();
  if (t < 12){
    float z = b2f(fb[t]);
    for (int j = 0; j < 128; j++) z += ps[j]*b2f(fw[t*128 + j]);
    float r = 1.f/(1.f + expf(-z));
    if (*fflag) ((float*)out)[g*12 + t] = r;
    else        ((ushort*)out)[g*12 + t] = f2b(r);
  }
}

__global__ __launch_bounds__(256) void k_sentinel(ushort* __restrict__ out, int n){
  int i = blockIdx.x*256 + threadIdx.x;
  if (i < n) out[i] = 0x3F00;
}

extern "C" void kernel_launch(void* const* d_in, const int* in_sizes, int n_in,
                              void* d_out, int out_size, void* d_ws, size_t ws_size,
                              hipStream_t stream){
  const void* x_raw   = d_in[0];
  const void* ei_raw  = d_in[1];
  const void* ea_raw  = d_in[2];
  const void* ba_raw  = d_in[3];
  (void)n_in;

  const int N = in_sizes[3];        // 20000
  const int E = in_sizes[1] / 2;    // 200000
  const int G = out_size / 12;      // 512

  // ---- workspace plan ----
  char* base = (char*)d_ws;
  size_t off = 0;
  auto alloc = [&](size_t bytes)->char*{
    char* p = base + off;
    off = (off + bytes + 255) & ~(size_t)255;
    return p;
  };
  int* iflag    = (int*)alloc(256);
  int* fflag    = (int*)alloc(256);
  int* deg      = (int*)alloc((size_t)N*4);
  int* fill     = (int*)alloc((size_t)N*4);
  int* rp       = (int*)alloc((size_t)(N+1)*4);
  int* batch2   = (int*)alloc((size_t)N*4);
  int* csrc     = (int*)alloc((size_t)E*4);
  int* ceid     = (int*)alloc((size_t)E*4);
  ushort* new_c = (ushort*)alloc(8192*2);
  ushort* w1c[3], *w2c[3];
  const int w1n[3] = {512*528, 512*528, 256*528};
  const int w2n[3] = {256*512, 256*512, 128*256};
  for (int i = 0; i < 3; i++) w1c[i] = (ushort*)alloc((size_t)w1n[i]*2);
  for (int i = 0; i < 3; i++) w2c[i] = (ushort*)alloc((size_t)w2n[i]*2);
  ushort* smallp = (ushort*)alloc(8192*2);
  float*  e_h32 = (float*)alloc((size_t)E*16*4);    // 12.8 MB, pre-unpacked f32
  ushort* h     = (ushort*)alloc((size_t)N*256*2);
  ushort* Q     = (ushort*)alloc((size_t)N*512*2);
  ushort* PM    = (ushort*)alloc((size_t)N*512*2);

  if (off > ws_size){
    k_sentinel<<<(out_size + 255)/256, 256, 0, stream>>>((ushort*)d_out, out_size);
    return;
  }

  // ---- probes + CSR ----
  k_probes<<<1, 256, 0, stream>>>((const uint*)ei_raw, (const uint*)x_raw, iflag, fflag);
  k_canon<<<(N + 255)/256, 256, 0, stream>>>(ba_raw, iflag, batch2, N);
  hipMemsetAsync(deg,  0, (size_t)N*4, stream);
  hipMemsetAsync(fill, 0, (size_t)N*4, stream);
  k_count<<<(E + 255)/256, 256, 0, stream>>>(ei_raw, iflag, deg, E, N);
  k_scan<<<1, 1024, 0, stream>>>(deg, rp, N);
  k_fill<<<(E + 255)/256, 256, 0, stream>>>(ei_raw, iflag, rp, fill, csrc, ceid, E, N);

  // ---- batched weight conversion (w1 x3, w2 x3, ne_w) ----
  CvtTab ct; ct.nseg = 7;
  const void* csrcs[7] = {d_in[8], d_in[16], d_in[24], d_in[10], d_in[18], d_in[26], d_in[6]};
  ushort* cdsts[7]     = {w1c[0],  w1c[1],   w1c[2],   w2c[0],   w2c[1],   w2c[2],   new_c};
  const int cns[7]     = {w1n[0],  w1n[1],   w1n[2],   w2n[0],   w2n[1],   w2n[2],   8192};
  int bacc = 0;
  for (int i = 0; i < 7; i++){
    ct.src[i] = csrcs[i]; ct.dst[i] = cdsts[i]; ct.n[i] = cns[i];
    ct.bstart[i] = bacc; bacc += (cns[i] + 8191)/8192;
  }
  k_cvt_batch<<<bacc, 256, 0, stream>>>(ct, fflag);

  // ---- small vectors packed ----
  SmallTab tab;
  int scount = 0, spos = 0;
  auto addsmall = [&](int di, int n)->int{
    int p = spos;
    tab.src[scount] = d_in[di]; tab.doff[scount] = spos; tab.n[scount] = n;
    spos += n; scount++;
    return p;
  };
  int pos_eew  = addsmall(4, 128);
  int pos_eeb  = addsmall(5, 16);
  int pos_neb  = addsmall(7, 256);
  int pos_b1[3], pos_b2[3], pos_g[3], pos_bb[3], pos_m[3], pos_v[3];
  const int b1n[3] = {512,512,256}, b2n[3] = {256,256,128}, bnn[3] = {256,256,128};
  for (int i = 0; i < 3; i++){
    int di = 8 + 8*i;
    pos_b1[i] = addsmall(di+1, b1n[i]);
    pos_b2[i] = addsmall(di+3, b2n[i]);
    pos_g[i]  = addsmall(di+4, bnn[i]);
    pos_bb[i] = addsmall(di+5, bnn[i]);
    pos_m[i]  = addsmall(di+6, bnn[i]);
    pos_v[i]  = addsmall(di+7, bnn[i]);
  }
  int pos_fcw = addsmall(32, 12*128);
  int pos_fcb = addsmall(33, 12);
  k_cvt_small<<<scount, 256, 0, stream>>>(tab, fflag, smallp, scount);

  // ---- encoders ----
  k_edge_enc<<<(E + 255)/256, 256, 0, stream>>>(ea_raw, smallp + pos_eew, smallp + pos_eeb, fflag, e_h32, E);
  k_node_enc<<<N, 256, 0, stream>>>(x_raw, new_c, smallp + pos_neb, fflag, h, N);

  // ---- 3 conv layers ----
  const int Cch[3] = {512, 512, 256};
  const int Od[3]  = {256, 256, 128};
  for (int i = 0; i < 3; i++){
    dim3 g1((N + 127)/128, 2*(Cch[i]/64));
    k_gemm_pq<<<g1, 256, 0, stream>>>(h, w1c[i], N, Cch[i], PM, Q);
    if (i < 2) k_msg3<512><<<N, 256, 0, stream>>>(PM, Q, e_h32, w1c[i], smallp + pos_b1[i], rp, csrc, ceid, PM, N);
    else       k_msg3<256><<<N, 128, 0, stream>>>(PM, Q, e_h32, w1c[i], smallp + pos_b1[i], rp, csrc, ceid, PM, N);
    dim3 g2((N + 127)/128, Od[i]/64);
    k_gemm_bn<<<g2, 256, 0, stream>>>(PM, Cch[i], w2c[i], Cch[i], N, Od[i], Cch[i],
                                      smallp + pos_b2[i], smallp + pos_g[i], smallp + pos_bb[i],
                                      smallp + pos_m[i],  smallp + pos_v[i], rp, h);
  }

  // ---- mean pool + FC + sigmoid ----
  k_pool<<<G, 128, 0, stream>>>(h, batch2, smallp + pos_fcw, smallp + pos_fcb, fflag, d_out, N);
}

// Round 6
// 626.044 us; speedup vs baseline: 1.3404x; 1.0805x over previous
//
// GCNTox21 fused pipeline — MI355X/gfx950.  R6: k_msg4 = barrier-free 4-node
// blocks (amortize wc/b1 preload) + 2-edge ILP unroll (hide scalar-load
// latency) + fused int2 CSR (one s_load per edge).  GEMMs untouched so the
// next profile surfaces them.
// Math (exact algebraic refactor):
//   P = h@w1[:,:in].T, Q = h@w1[:,in:2in].T    (node GEMMs, MFMA bf16)
//   u_e = relu(P[dst] + Q[src] + e_h[e]@w1[:,2in:].T + b1)
//   mean_u[n] = mean_{e:dst=n} u_e             (CSR over dst, built once)
//   h' = relu(BN(mean_u@w2.T + b2)), deg==0 rows -> BN(0)
//   out = sigmoid(mean_pool(h)@fc.T + fc_b)
#include <hip/hip_runtime.h>
#include <hip/hip_bf16.h>

typedef unsigned int  uint;
typedef unsigned short ushort;
typedef float  f32x2  __attribute__((ext_vector_type(2)));
typedef float  f32x4  __attribute__((ext_vector_type(4)));
typedef __bf16 bf16x8 __attribute__((ext_vector_type(8)));

#define DEV static __device__ __forceinline__

DEV float  b2f(ushort b){ return __uint_as_float(((uint)b) << 16); }
DEV float  lo2f(uint u){ return __uint_as_float(u << 16); }
DEV float  hi2f(uint u){ return __uint_as_float(u & 0xffff0000u); }
DEV ushort f2b(float f){           // RNE float->bf16
  uint u = __float_as_uint(f);
  u += 0x7fffu + ((u >> 16) & 1u);
  return (ushort)(u >> 16);
}
DEV uint pk2(float a, float b){ return (uint)f2b(a) | ((uint)f2b(b) << 16); }
DEV void unpack8(uint4 v, float* f){
  f[0]=lo2f(v.x); f[1]=hi2f(v.x); f[2]=lo2f(v.y); f[3]=hi2f(v.y);
  f[4]=lo2f(v.z); f[5]=hi2f(v.z); f[6]=lo2f(v.w); f[7]=hi2f(v.w);
}
DEV int ld_idx(const void* p, int flag, long long i){
  return flag ? ((const int*)p)[i] : (int)((const long long*)p)[i];
}
DEV int clampi(int v, int lo, int hi){ return v < lo ? lo : (v > hi ? hi : v); }

// ---------- merged probes: int64/int32 index layout + fp32/bf16 float layout ----------
__global__ void k_probes(const uint* __restrict__ ei, const uint* __restrict__ xw,
                         int* __restrict__ iflag, int* __restrict__ fflag){
  __shared__ int anyI, cntF;
  if (threadIdx.x == 0){ anyI = 0; cntF = 0; }
  __syncthreads();
  int li = 0, lc = 0;
  for (int i = threadIdx.x; i < 1024; i += 256){
    if (ei[2*i + 1] != 0u) li = 1;            // int64 => odd words all 0
    float f = fabsf(__uint_as_float(xw[i]));  // fp32 N(0,1) words decode sane
    if (f > 1e-6f && f < 1e6f) lc++;
  }
  if (li) atomicOr(&anyI, 1);
  atomicAdd(&cntF, lc);
  __syncthreads();
  if (threadIdx.x == 0){ *iflag = anyI; *fflag = (2*cntF > 1024) ? 1 : 0; }
}

// ---------- canonicalization ----------
__global__ __launch_bounds__(256) void k_canon(const void* __restrict__ src,
    const int* __restrict__ flag, int* __restrict__ out, int n){
  int i = blockIdx.x*256 + threadIdx.x;
  if (i >= n) return;
  out[i] = ld_idx(src, *flag, i);
}

struct CvtTab { const void* src[8]; ushort* dst[8]; int n[8]; int bstart[8]; int nseg; };
__global__ __launch_bounds__(256) void k_cvt_batch(CvtTab tab, const int* __restrict__ flag){
  int b = blockIdx.x;
  int s = tab.nseg - 1;
  for (int i = 1; i < tab.nseg; i++) if (b < tab.bstart[i]){ s = i - 1; break; }
  int rel = b - tab.bstart[s];
  const void* sp = tab.src[s];
  ushort* d = tab.dst[s];
  int f = *flag;
  int end = tab.n[s]; int cap = rel*8192 + 8192; if (cap < end) end = cap;
  for (int i = rel*8192 + threadIdx.x; i < end; i += 256)
    d[i] = f ? f2b(((const float*)sp)[i]) : ((const ushort*)sp)[i];
}

struct SmallTab { const void* src[24]; int doff[24]; int n[24]; };
__global__ __launch_bounds__(256) void k_cvt_small(SmallTab tab, const int* __restrict__ flag,
    ushort* __restrict__ base, int cnt){
  int b = blockIdx.x;
  if (b >= cnt) return;
  int f = *flag;
  const void* s = tab.src[b];
  ushort* d = base + tab.doff[b];
  for (int i = threadIdx.x; i < tab.n[b]; i += 256)
    d[i] = f ? f2b(((const float*)s)[i]) : ((const ushort*)s)[i];
}

// ---------- CSR build over dst ----------
__global__ __launch_bounds__(256) void k_count(const void* __restrict__ ei,
    const int* __restrict__ flag, int* __restrict__ cnt, int E, int N){
  int e = blockIdx.x*256 + threadIdx.x;
  if (e >= E) return;
  int d = clampi(ld_idx(ei, *flag, (long long)E + e), 0, N-1);
  atomicAdd(&cnt[d], 1);
}

__global__ __launch_bounds__(1024) void k_scan(const int* __restrict__ deg, int* __restrict__ rp, int n){
  __shared__ int part[1024];
  int t = threadIdx.x;
  int chunk = (n + 1023) >> 10;
  int base = t * chunk;
  int s = 0;
  for (int i = 0; i < chunk; i++){ int j = base + i; if (j < n) s += deg[j]; }
  part[t] = s;
  __syncthreads();
  for (int off = 1; off < 1024; off <<= 1){
    int v = (t >= off) ? part[t - off] : 0;
    __syncthreads();
    part[t] += v;
    __syncthreads();
  }
  int run = part[t] - s;
  for (int i = 0; i < chunk; i++){ int j = base + i; if (j < n){ rp[j] = run; run += deg[j]; } }
  if (t == 1023) rp[n] = part[1023];
}

__global__ __launch_bounds__(256) void k_fill(const void* __restrict__ ei,
    const int* __restrict__ flag, const int* __restrict__ rp, int* __restrict__ fill,
    int2* __restrict__ cpair, int E, int N){
  int e = blockIdx.x*256 + threadIdx.x;
  if (e >= E) return;
  int f = *flag;
  int s = clampi(ld_idx(ei, f, e), 0, N-1);
  int d = clampi(ld_idx(ei, f, (long long)E + e), 0, N-1);
  int pos = clampi(rp[d] + atomicAdd(&fill[d], 1), 0, E-1);
  cpair[pos] = make_int2(s, e);
}

// ---------- encoders ----------
// e_h32[E,16] = relu(edge_attr @ ee_w.T + ee_b), stored PRE-UNPACKED f32
__global__ __launch_bounds__(256) void k_edge_enc(const void* __restrict__ ea,
    const ushort* __restrict__ w, const ushort* __restrict__ b,
    const int* __restrict__ fflag, float* __restrict__ eh, int E){
  __shared__ float ws[128];
  __shared__ float bs[16];
  int t = threadIdx.x;
  if (t < 128) ws[t] = b2f(w[t]);
  if (t < 16)  bs[t] = b2f(b[t]);
  int f = *fflag;
  __syncthreads();
  int e = blockIdx.x*256 + t;
  if (e >= E) return;
  float a[8];
  if (f){
    const float4* ap = (const float4*)((const float*)ea + (size_t)e*8);
    float4 v0 = ap[0], v1 = ap[1];
    a[0]=v0.x; a[1]=v0.y; a[2]=v0.z; a[3]=v0.w;
    a[4]=v1.x; a[5]=v1.y; a[6]=v1.z; a[7]=v1.w;
  } else {
    uint4 av = *(const uint4*)((const ushort*)ea + (size_t)e*8);
    unpack8(av, a);
  }
  float o[16];
  #pragma unroll
  for (int c = 0; c < 16; c++){
    float s = bs[c];
    #pragma unroll
    for (int j = 0; j < 8; j++) s += a[j]*ws[c*8+j];
    o[c] = fmaxf(s, 0.f);
  }
  f32x4* op = (f32x4*)(eh + (size_t)e*16);
  #pragma unroll
  for (int q4 = 0; q4 < 4; q4++){
    f32x4 v = {o[q4*4+0], o[q4*4+1], o[q4*4+2], o[q4*4+3]};
    op[q4] = v;
  }
}

__global__ __launch_bounds__(256) void k_node_enc(const void* __restrict__ x,
    const ushort* __restrict__ w, const ushort* __restrict__ b,
    const int* __restrict__ fflag, ushort* __restrict__ h, int N){
  __shared__ float xs[32];
  int n = blockIdx.x, t = threadIdx.x;
  int f = *fflag;
  if (t < 32) xs[t] = f ? ((const float*)x)[(size_t)n*32 + t]
                        : b2f(((const ushort*)x)[(size_t)n*32 + t]);
  __syncthreads();
  const uint4* wp = (const uint4*)(w + (size_t)t*32);
  float s = b2f(b[t]);
  #pragma unroll
  for (int q4 = 0; q4 < 4; q4++){
    uint4 u = wp[q4];
    int k = q4*8;
    s += xs[k+0]*lo2f(u.x) + xs[k+1]*hi2f(u.x)
       + xs[k+2]*lo2f(u.y) + xs[k+3]*hi2f(u.y)
       + xs[k+4]*lo2f(u.z) + xs[k+5]*hi2f(u.z)
       + xs[k+6]*lo2f(u.w) + xs[k+7]*hi2f(u.w);
  }
  h[(size_t)n*256 + t] = f2b(fmaxf(s, 0.f));
}

// ---------- merged P/Q GEMM, 32-row waves ----------
__global__ __launch_bounds__(256) void k_gemm_pq(const ushort* __restrict__ A,
    const ushort* __restrict__ w1, int M, int Nc,
    ushort* __restrict__ P, ushort* __restrict__ Q){
  const int l  = threadIdx.x & 63;
  const int wv = threadIdx.x >> 6;
  const int m0 = blockIdx.x*128 + wv*32;
  const int yc = Nc >> 6;
  const int isQ = (int)blockIdx.y >= yc;
  const int n0 = (isQ ? blockIdx.y - yc : blockIdx.y)*64;
  const ushort* W = w1 + (isQ ? 256 : 0);
  ushort* C = isQ ? Q : P;
  const int lr = l & 15;
  const int q  = l >> 4;
  int ar0 = m0 + lr;      if (ar0 >= M) ar0 = M - 1;
  int ar1 = m0 + 16 + lr; if (ar1 >= M) ar1 = M - 1;
  const ushort* Ap0 = A + (size_t)ar0*256 + q*8;
  const ushort* Ap1 = A + (size_t)ar1*256 + q*8;
  const ushort* Wp = W + (size_t)(n0 + lr)*528 + q*8;
  f32x4 acc[2][4];
  #pragma unroll
  for (int f = 0; f < 2; f++)
    #pragma unroll
    for (int nf = 0; nf < 4; nf++) acc[f][nf] = {0.f,0.f,0.f,0.f};
  #pragma unroll
  for (int k = 0; k < 256; k += 32){
    bf16x8 a0 = *(const bf16x8*)(Ap0 + k);
    bf16x8 a1 = *(const bf16x8*)(Ap1 + k);
    #pragma unroll
    for (int nf = 0; nf < 4; nf++){
      bf16x8 b = *(const bf16x8*)(Wp + (size_t)nf*16*528 + k);
      acc[0][nf] = __builtin_amdgcn_mfma_f32_16x16x32_bf16(a0, b, acc[0][nf], 0, 0, 0);
      acc[1][nf] = __builtin_amdgcn_mfma_f32_16x16x32_bf16(a1, b, acc[1][nf], 0, 0, 0);
    }
  }
  #pragma unroll
  for (int f = 0; f < 2; f++){
    #pragma unroll
    for (int nf = 0; nf < 4; nf++){
      int col = n0 + nf*16 + lr;
      #pragma unroll
      for (int r = 0; r < 4; r++){
        int row = m0 + 16*f + q*4 + r;
        if (row < M) C[(size_t)row*Nc + col] = f2b(acc[f][nf][r]);
      }
    }
  }
}

// GEMM + bias + deg-mask + eval-BN + relu, 32-row waves
__global__ __launch_bounds__(256) void k_gemm_bn(const ushort* __restrict__ A, int lda,
    const ushort* __restrict__ W, int ldb, int M, int Nc, int K,
    const ushort* __restrict__ bias, const ushort* __restrict__ g, const ushort* __restrict__ bb,
    const ushort* __restrict__ rm, const ushort* __restrict__ rv,
    const int* __restrict__ rp, ushort* __restrict__ H){
  const int l  = threadIdx.x & 63;
  const int wv = threadIdx.x >> 6;
  const int m0 = blockIdx.x*128 + wv*32;
  const int n0 = blockIdx.y*64;
  const int lr = l & 15;
  const int q  = l >> 4;
  int ar0 = m0 + lr;      if (ar0 >= M) ar0 = M - 1;
  int ar1 = m0 + 16 + lr; if (ar1 >= M) ar1 = M - 1;
  const ushort* Ap0 = A + (size_t)ar0*lda + q*8;
  const ushort* Ap1 = A + (size_t)ar1*lda + q*8;
  const ushort* Wp = W + (size_t)(n0 + lr)*ldb + q*8;
  f32x4 acc[2][4];
  #pragma unroll
  for (int f = 0; f < 2; f++)
    #pragma unroll
    for (int nf = 0; nf < 4; nf++) acc[f][nf] = {0.f,0.f,0.f,0.f};
  for (int k = 0; k < K; k += 32){
    bf16x8 a0 = *(const bf16x8*)(Ap0 + k);
    bf16x8 a1 = *(const bf16x8*)(Ap1 + k);
    #pragma unroll
    for (int nf = 0; nf < 4; nf++){
      bf16x8 b = *(const bf16x8*)(Wp + (size_t)nf*16*ldb + k);
      acc[0][nf] = __builtin_amdgcn_mfma_f32_16x16x32_bf16(a0, b, acc[0][nf], 0, 0, 0);
      acc[1][nf] = __builtin_amdgcn_mfma_f32_16x16x32_bf16(a1, b, acc[1][nf], 0, 0, 0);
    }
  }
  #pragma unroll
  for (int nf = 0; nf < 4; nf++){
    int col = n0 + nf*16 + lr;
    float bi = b2f(bias[col]);
    float sc = b2f(g[col]) * rsqrtf(b2f(rv[col]) + 1e-5f);
    float sh = b2f(bb[col]) - b2f(rm[col]) * sc;
    #pragma unroll
    for (int f = 0; f < 2; f++){
      #pragma unroll
      for (int r = 0; r < 4; r++){
        int row = m0 + 16*f + q*4 + r;
        if (row < M){
          float v = acc[f][nf][r] + bi;
          if (rp[row+1] - rp[row] == 0) v = 0.f;   // empty segment: mean is 0
          H[(size_t)row*Nc + col] = f2b(fmaxf(v*sc + sh, 0.f));
        }
      }
    }
  }
}

// ---------- per-node edge aggregation v4 ----------
// 4 nodes/block, NO barriers/LDS; thread t owns channels {2t,2t+1} for all 4
// nodes (wc/b1 preload amortized).  2-edge unrolled inner loop: both edges'
// scalar e-row loads + Q gathers issue together (latency hiding via ILP).
// MU may alias P: block touches only its 4 rows, read-before-write per thread.
template<int C>
__global__ __launch_bounds__(256) void k_msg4(const ushort* P, const ushort* __restrict__ Q,
    const float* __restrict__ eh, const ushort* __restrict__ w1, const ushort* __restrict__ b1,
    const int* __restrict__ rp, const int2* __restrict__ cpair,
    ushort* MU, int N){
  int t = threadIdx.x;
  int c0 = t*2;
  f32x2 wc[16];
  {
    float a0[16], a1[16];
    const uint4* wp0 = (const uint4*)(w1 + (size_t)c0*528 + 512);
    const uint4* wp1 = (const uint4*)(w1 + (size_t)(c0+1)*528 + 512);
    unpack8(wp0[0], a0); unpack8(wp0[1], a0+8);
    unpack8(wp1[0], a1); unpack8(wp1[1], a1+8);
    #pragma unroll
    for (int j = 0; j < 16; j++){ wc[j].x = a0[j]; wc[j].y = a1[j]; }
  }
  uint bw = *(const uint*)(b1 + c0);
  f32x2 b1v = { lo2f(bw), hi2f(bw) };
  int nb = blockIdx.x*4;
  int ne = nb + 4; if (ne > N) ne = N;
  for (int n = nb; n < ne; n++){
    const int i0 = rp[n], i1 = rp[n+1];
    uint pw = *(const uint*)(P + (size_t)n*C + c0);
    f32x2 pre = { lo2f(pw) + b1v.x, hi2f(pw) + b1v.y };
    f32x2 acc0 = {0.f, 0.f}, acc1 = {0.f, 0.f};
    int i = i0;
    for (; i + 2 <= i1; i += 2){
      int2 p0 = cpair[i];
      int2 p1 = cpair[i+1];
      uint qw0 = *(const uint*)(Q + (size_t)p0.x*C + c0);
      uint qw1 = *(const uint*)(Q + (size_t)p1.x*C + c0);
      const f32x4* e0p = (const f32x4*)(eh + (size_t)p0.y*16);
      const f32x4* e1p = (const f32x4*)(eh + (size_t)p1.y*16);
      f32x4 ea0 = e0p[0], ea1 = e0p[1], ea2 = e0p[2], ea3 = e0p[3];
      f32x4 eb0 = e1p[0], eb1 = e1p[1], eb2 = e1p[2], eb3 = e1p[3];
      float ef0[16] = {ea0.x,ea0.y,ea0.z,ea0.w, ea1.x,ea1.y,ea1.z,ea1.w,
                       ea2.x,ea2.y,ea2.z,ea2.w, ea3.x,ea3.y,ea3.z,ea3.w};
      float ef1[16] = {eb0.x,eb0.y,eb0.z,eb0.w, eb1.x,eb1.y,eb1.z,eb1.w,
                       eb2.x,eb2.y,eb2.z,eb2.w, eb3.x,eb3.y,eb3.z,eb3.w};
      f32x2 d0 = { pre.x + lo2f(qw0), pre.y + hi2f(qw0) };
      f32x2 d1 = { pre.x + lo2f(qw1), pre.y + hi2f(qw1) };
      #pragma unroll
      for (int j = 0; j < 16; j++){
        f32x2 e0v = {ef0[j], ef0[j]};
        f32x2 e1v = {ef1[j], ef1[j]};
        d0 += wc[j] * e0v;
        d1 += wc[j] * e1v;
      }
      acc0.x += fmaxf(d0.x, 0.f); acc0.y += fmaxf(d0.y, 0.f);
      acc1.x += fmaxf(d1.x, 0.f); acc1.y += fmaxf(d1.y, 0.f);
    }
    if (i < i1){
      int2 p0 = cpair[i];
      uint qw0 = *(const uint*)(Q + (size_t)p0.x*C + c0);
      const f32x4* e0p = (const f32x4*)(eh + (size_t)p0.y*16);
      f32x4 ea0 = e0p[0], ea1 = e0p[1], ea2 = e0p[2], ea3 = e0p[3];
      float ef0[16] = {ea0.x,ea0.y,ea0.z,ea0.w, ea1.x,ea1.y,ea1.z,ea1.w,
                       ea2.x,ea2.y,ea2.z,ea2.w, ea3.x,ea3.y,ea3.z,ea3.w};
      f32x2 d0 = { pre.x + lo2f(qw0), pre.y + hi2f(qw0) };
      #pragma unroll
      for (int j = 0; j < 16; j++){
        f32x2 e0v = {ef0[j], ef0[j]};
        d0 += wc[j] * e0v;
      }
      acc0.x += fmaxf(d0.x, 0.f); acc0.y += fmaxf(d0.y, 0.f);
    }
    int cnt = i1 - i0;
    float inv = (cnt > 0) ? 1.f/(float)cnt : 0.f;
    *(uint*)(MU + (size_t)n*C + c0) = pk2((acc0.x + acc1.x)*inv, (acc0.y + acc1.y)*inv);
  }
}

// ---------- pooling + FC + sigmoid ----------
__global__ __launch_bounds__(128) void k_pool(const ushort* __restrict__ h, const int* __restrict__ batch,
    const ushort* __restrict__ fw, const ushort* __restrict__ fb,
    const int* __restrict__ fflag, void* __restrict__ out, int N){
  int g = blockIdx.x, t = threadIdx.x;
  int lo = 0, hi = N;
  while (lo < hi){ int mid = (lo+hi) >> 1; if (batch[mid] <  g) lo = mid+1; else hi = mid; }
  int s0 = lo;
  hi = N;
  while (lo < hi){ int mid = (lo+hi) >> 1; if (batch[mid] <= g) lo = mid+1; else hi = mid; }
  int s1 = lo;
  float s = 0.f;
  for (int i = s0; i < s1; i++) s += b2f(h[(size_t)i*128 + t]);
  int cnt = s1 - s0;
  __shared__ float ps[128];
  ps[t] = s / (float)(cnt > 0 ? cnt : 1);
  __syncthreads();
  if (t < 12){
    float z = b2f(fb[t]);
    for (int j = 0; j < 128; j++) z += ps[j]*b2f(fw[t*128 + j]);
    float r = 1.f/(1.f + expf(-z));
    if (*fflag) ((float*)out)[g*12 + t] = r;
    else        ((ushort*)out)[g*12 + t] = f2b(r);
  }
}

__global__ __launch_bounds__(256) void k_sentinel(ushort* __restrict__ out, int n){
  int i = blockIdx.x*256 + threadIdx.x;
  if (i < n) out[i] = 0x3F00;
}

extern "C" void kernel_launch(void* const* d_in, const int* in_sizes, int n_in,
                              void* d_out, int out_size, void* d_ws, size_t ws_size,
                              hipStream_t stream){
  const void* x_raw   = d_in[0];
  const void* ei_raw  = d_in[1];
  const void* ea_raw  = d_in[2];
  const void* ba_raw  = d_in[3];
  (void)n_in;

  const int N = in_sizes[3];        // 20000
  const int E = in_sizes[1] / 2;    // 200000
  const int G = out_size / 12;      // 512

  // ---- workspace plan ----
  char* base = (char*)d_ws;
  size_t off = 0;
  auto alloc = [&](size_t bytes)->char*{
    char* p = base + off;
    off = (off + bytes + 255) & ~(size_t)255;
    return p;
  };
  int* iflag    = (int*)alloc(256);
  int* fflag    = (int*)alloc(256);
  int* deg      = (int*)alloc((size_t)N*4);
  int* fill     = (int*)alloc((size_t)N*4);
  int* rp       = (int*)alloc((size_t)(N+1)*4);
  int* batch2   = (int*)alloc((size_t)N*4);
  int2* cpair   = (int2*)alloc((size_t)E*8);
  ushort* new_c = (ushort*)alloc(8192*2);
  ushort* w1c[3], *w2c[3];
  const int w1n[3] = {512*528, 512*528, 256*528};
  const int w2n[3] = {256*512, 256*512, 128*256};
  for (int i = 0; i < 3; i++) w1c[i] = (ushort*)alloc((size_t)w1n[i]*2);
  for (int i = 0; i < 3; i++) w2c[i] = (ushort*)alloc((size_t)w2n[i]*2);
  ushort* smallp = (ushort*)alloc(8192*2);
  float*  e_h32 = (float*)alloc((size_t)E*16*4);    // 12.8 MB, pre-unpacked f32
  ushort* h     = (ushort*)alloc((size_t)N*256*2);
  ushort* Q     = (ushort*)alloc((size_t)N*512*2);
  ushort* PM    = (ushort*)alloc((size_t)N*512*2);

  if (off > ws_size){
    k_sentinel<<<(out_size + 255)/256, 256, 0, stream>>>((ushort*)d_out, out_size);
    return;
  }

  // ---- probes + CSR ----
  k_probes<<<1, 256, 0, stream>>>((const uint*)ei_raw, (const uint*)x_raw, iflag, fflag);
  k_canon<<<(N + 255)/256, 256, 0, stream>>>(ba_raw, iflag, batch2, N);
  hipMemsetAsync(deg,  0, (size_t)N*4, stream);
  hipMemsetAsync(fill, 0, (size_t)N*4, stream);
  k_count<<<(E + 255)/256, 256, 0, stream>>>(ei_raw, iflag, deg, E, N);
  k_scan<<<1, 1024, 0, stream>>>(deg, rp, N);
  k_fill<<<(E + 255)/256, 256, 0, stream>>>(ei_raw, iflag, rp, fill, cpair, E, N);

  // ---- batched weight conversion (w1 x3, w2 x3, ne_w) ----
  CvtTab ct; ct.nseg = 7;
  const void* csrcs[7] = {d_in[8], d_in[16], d_in[24], d_in[10], d_in[18], d_in[26], d_in[6]};
  ushort* cdsts[7]     = {w1c[0],  w1c[1],   w1c[2],   w2c[0],   w2c[1],   w2c[2],   new_c};
  const int cns[7]     = {w1n[0],  w1n[1],   w1n[2],   w2n[0],   w2n[1],   w2n[2],   8192};
  int bacc = 0;
  for (int i = 0; i < 7; i++){
    ct.src[i] = csrcs[i]; ct.dst[i] = cdsts[i]; ct.n[i] = cns[i];
    ct.bstart[i] = bacc; bacc += (cns[i] + 8191)/8192;
  }
  k_cvt_batch<<<bacc, 256, 0, stream>>>(ct, fflag);

  // ---- small vectors packed ----
  SmallTab tab;
  int scount = 0, spos = 0;
  auto addsmall = [&](int di, int n)->int{
    int p = spos;
    tab.src[scount] = d_in[di]; tab.doff[scount] = spos; tab.n[scount] = n;
    spos += n; scount++;
    return p;
  };
  int pos_eew  = addsmall(4, 128);
  int pos_eeb  = addsmall(5, 16);
  int pos_neb  = addsmall(7, 256);
  int pos_b1[3], pos_b2[3], pos_g[3], pos_bb[3], pos_m[3], pos_v[3];
  const int b1n[3] = {512,512,256}, b2n[3] = {256,256,128}, bnn[3] = {256,256,128};
  for (int i = 0; i < 3; i++){
    int di = 8 + 8*i;
    pos_b1[i] = addsmall(di+1, b1n[i]);
    pos_b2[i] = addsmall(di+3, b2n[i]);
    pos_g[i]  = addsmall(di+4, bnn[i]);
    pos_bb[i] = addsmall(di+5, bnn[i]);
    pos_m[i]  = addsmall(di+6, bnn[i]);
    pos_v[i]  = addsmall(di+7, bnn[i]);
  }
  int pos_fcw = addsmall(32, 12*128);
  int pos_fcb = addsmall(33, 12);
  k_cvt_small<<<scount, 256, 0, stream>>>(tab, fflag, smallp, scount);

  // ---- encoders ----
  k_edge_enc<<<(E + 255)/256, 256, 0, stream>>>(ea_raw, smallp + pos_eew, smallp + pos_eeb, fflag, e_h32, E);
  k_node_enc<<<N, 256, 0, stream>>>(x_raw, new_c, smallp + pos_neb, fflag, h, N);

  // ---- 3 conv layers ----
  const int Cch[3] = {512, 512, 256};
  const int Od[3]  = {256, 256, 128};
  for (int i = 0; i < 3; i++){
    dim3 g1((N + 127)/128, 2*(Cch[i]/64));
    k_gemm_pq<<<g1, 256, 0, stream>>>(h, w1c[i], N, Cch[i], PM, Q);
    dim3 gm((N + 3)/4);
    if (i < 2) k_msg4<512><<<gm, 256, 0, stream>>>(PM, Q, e_h32, w1c[i], smallp + pos_b1[i], rp, cpair, PM, N);
    else       k_msg4<256><<<gm, 128, 0, stream>>>(PM, Q, e_h32, w1c[i], smallp + pos_b1[i], rp, cpair, PM, N);
    dim3 g2((N + 127)/128, Od[i]/64);
    k_gemm_bn<<<g2, 256, 0, stream>>>(PM, Cch[i], w2c[i], Cch[i], N, Od[i], Cch[i],
                                      smallp + pos_b2[i], smallp + pos_g[i], smallp + pos_bb[i],
                                      smallp + pos_m[i],  smallp + pos_v[i], rp, h);
  }

  // ---- mean pool + FC + sigmoid ----
  k_pool<<<G, 128, 0, stream>>>(h, batch2, smallp + pos_fcw, smallp + pos_fcb, fflag, d_out, N);
}